// Round 1
// 528.177 us; speedup vs baseline: 1.0034x; 1.0034x over previous
//
#include <hip/hip_runtime.h>

#define DIM 4096
#define NH 32
#define NKV 8
#define HD 128
#define WINDOW 1024
#define SEQ 2048
#define QLD 6144  // fused QKV row stride (u16 elems)

typedef unsigned int uint32;
typedef __attribute__((ext_vector_type(8))) short short8_t;
typedef __attribute__((ext_vector_type(8))) __bf16 bf16x8_t;
typedef __attribute__((ext_vector_type(4))) float floatx4_t;

__device__ __forceinline__ uint32 f2bf_bits(float f) {
  uint32 u = __builtin_bit_cast(uint32, f);
  return (u + 0x7fffu + ((u >> 16) & 1u)) >> 16;
}
__device__ __forceinline__ float bf2f(unsigned short b) {
  return __builtin_bit_cast(float, ((uint32)b) << 16);
}

template <class X, class Y> struct same_t { static constexpr bool v = false; };
template <class X> struct same_t<X, X> { static constexpr bool v = true; };

__device__ __forceinline__ void load_lds16(const unsigned short* g, unsigned short* l) {
  __builtin_amdgcn_global_load_lds((__attribute__((address_space(1))) void*)g,
                                   (__attribute__((address_space(3))) void*)l, 16, 0, 0);
}

// ============================================================================
// bf16 GEMM (m97-style): C[M,N] = A[M,K]*B[N,K]^T, global_load_lds width-16
// staging, XOR col8 swizzle, 128x128 tile, BK=64, 4 waves x (4x4) MFMA.
// ROPE=true: apply rotary embedding in the epilogue for cols < rope_ncols
// (pair (2d,2d+1) lives in lanes l16^1 -> one shfl_xor; applied to fp32 acc
// before the single bf16 round).
// ============================================================================
template <typename TC, bool ROPE>
__global__ __launch_bounds__(256) void gemm_bf16(const unsigned short* __restrict__ A,
                                                 const unsigned short* __restrict__ B,
                                                 TC* __restrict__ C,
                                                 int M, int N, int K,
                                                 const float* __restrict__ cosp,
                                                 const float* __restrict__ sinp,
                                                 int rope_ncols) {
  __shared__ unsigned short As[128 * 64];
  __shared__ unsigned short Bs[128 * 64];
  const int tid = threadIdx.x;
  const int lane = tid & 63, w = tid >> 6;
  const int quad = lane >> 4, l16 = lane & 15;
  const int wm = w >> 1, wn = w & 1;
  const size_t m0 = (size_t)blockIdx.y * 128, n0 = (size_t)blockIdx.x * 128;

  const int srow = tid >> 3;
  const int scol = ((tid & 7) ^ (srow & 7)) << 3;
  const unsigned short* Abase = A + (m0 + srow) * (size_t)K + scol;
  const unsigned short* Bbase = B + (n0 + srow) * (size_t)K + scol;
  unsigned short* ldsA = As + (tid >> 6) * 512;
  unsigned short* ldsB = Bs + (tid >> 6) * 512;

  const int sa = l16 & 7;
  const int raA = wm * 64 + l16;
  const int raB = wn * 64 + l16;

  floatx4_t acc[4][4] = {};

  const int nk = K >> 6;
  for (int kt = 0; kt < nk; kt++) {
    const int kbase = kt << 6;
#pragma unroll
    for (int i = 0; i < 4; i++) {
      load_lds16(Abase + kbase + (size_t)(i * 32) * K, ldsA + i * 2048);
      load_lds16(Bbase + kbase + (size_t)(i * 32) * K, ldsB + i * 2048);
    }
    __syncthreads();
#pragma unroll
    for (int ks = 0; ks < 2; ks++) {
      bf16x8_t af[4], bfg[4];
#pragma unroll
      for (int i = 0; i < 4; i++) {
        const int colA = (((ks << 2) | quad) ^ sa) << 3;
        af[i] = __builtin_bit_cast(bf16x8_t,
            *(const short8_t*)(&As[(raA + i * 16) * 64 + colA]));
      }
#pragma unroll
      for (int j = 0; j < 4; j++) {
        const int colB = (((ks << 2) | quad) ^ sa) << 3;
        bfg[j] = __builtin_bit_cast(bf16x8_t,
            *(const short8_t*)(&Bs[(raB + j * 16) * 64 + colB]));
      }
#pragma unroll
      for (int i = 0; i < 4; i++)
#pragma unroll
        for (int j = 0; j < 4; j++)
          acc[i][j] = __builtin_amdgcn_mfma_f32_16x16x32_bf16(af[i], bfg[j], acc[i][j], 0, 0, 0);
    }
    __syncthreads();
  }
#pragma unroll
  for (int i = 0; i < 4; i++)
#pragma unroll
    for (int j = 0; j < 4; j++) {
      const int colb = (int)n0 + wn * 64 + j * 16;  // wave-uniform
      const bool do_rope = ROPE && (colb < rope_ncols);
#pragma unroll
      for (int r = 0; r < 4; r++) {
        size_t row = m0 + wm * 64 + i * 16 + quad * 4 + r;
        size_t col = n0 + wn * 64 + j * 16 + l16;
        float v = acc[i][j][r];
        if constexpr (ROPE) {
          if (do_rope) {  // wave-uniform branch (16-col tile never straddles 5120)
            float pv = __shfl_xor(v, 1);
            const int d = ((int)col & 127) >> 1;
            const float c = cosp[row * 64 + d];
            const float s = sinp[row * 64 + d];
            v = ((int)col & 1) ? (pv * s + v * c) : (v * c - pv * s);
          }
        }
        if constexpr (same_t<TC, float>::v)
          C[row * (size_t)N + col] = v;
        else
          C[row * (size_t)N + col] = (unsigned short)f2bf_bits(v);
      }
    }
}

// fp32 -> bf16 convert, 8 elems/thread
__global__ __launch_bounds__(256) void cvt_kernel(const float* __restrict__ in,
                                                  unsigned short* __restrict__ out, int n8) {
  int idx = blockIdx.x * 256 + threadIdx.x;
  if (idx >= n8) return;
  const float4* p = (const float4*)in + (size_t)idx * 2;
  float4 a = p[0], b = p[1];
  uint32 w0 = f2bf_bits(a.x) | (f2bf_bits(a.y) << 16);
  uint32 w1 = f2bf_bits(a.z) | (f2bf_bits(a.w) << 16);
  uint32 w2 = f2bf_bits(b.x) | (f2bf_bits(b.y) << 16);
  uint32 w3 = f2bf_bits(b.z) | (f2bf_bits(b.w) << 16);
  ((uint4*)out)[idx] = make_uint4(w0, w1, w2, w3);
}

// Merged fp32->bf16 convert for {x, wq, wk, wv}: region-dispatched by block.
// Block counts: x 4096, wq 8192, wk 2048, wv 2048 (all exact multiples).
__global__ __launch_bounds__(256) void cvt4_kernel(const float* __restrict__ s0,
                                                   const float* __restrict__ s1,
                                                   const float* __restrict__ s2,
                                                   const float* __restrict__ s3,
                                                   unsigned short* __restrict__ d0,
                                                   unsigned short* __restrict__ d1,
                                                   unsigned short* __restrict__ d2,
                                                   unsigned short* __restrict__ d3) {
  const int b = blockIdx.x;
  const float* src;
  unsigned short* dst;
  int rb;
  if (b < 4096)        { src = s0; dst = d0; rb = b; }
  else if (b < 12288)  { src = s1; dst = d1; rb = b - 4096; }
  else if (b < 14336)  { src = s2; dst = d2; rb = b - 12288; }
  else                 { src = s3; dst = d3; rb = b - 14336; }
  const int idx = rb * 256 + threadIdx.x;
  const float4* p = (const float4*)src + (size_t)idx * 2;
  float4 a = p[0], bb = p[1];
  uint32 w0 = f2bf_bits(a.x) | (f2bf_bits(a.y) << 16);
  uint32 w1 = f2bf_bits(a.z) | (f2bf_bits(a.w) << 16);
  uint32 w2 = f2bf_bits(bb.x) | (f2bf_bits(bb.y) << 16);
  uint32 w3 = f2bf_bits(bb.z) | (f2bf_bits(bb.w) << 16);
  ((uint4*)dst)[idx] = make_uint4(w0, w1, w2, w3);
}

// v [s][r] (ld QLD, v = qkvb col 5120) -> vT [r][s], 64x64 LDS tiles
__global__ __launch_bounds__(256) void vtrans_kernel(const unsigned short* __restrict__ v,
                                                     unsigned short* __restrict__ vT) {
  __shared__ unsigned short t[64][72];
  const int s0 = blockIdx.y * 64, r0 = blockIdx.x * 64;
  const int tid = threadIdx.x;
#pragma unroll
  for (int it = 0; it < 2; it++) {
    int f = it * 256 + tid;
    int si = f >> 3, cj = (f & 7) << 3;
    *(short8_t*)(&t[si][cj]) = *(const short8_t*)(v + (size_t)(s0 + si) * QLD + r0 + cj);
  }
  __syncthreads();
#pragma unroll
  for (int it = 0; it < 2; it++) {
    int f = it * 256 + tid;
    int ri = f >> 3, sj = (f & 7) << 3;
    short8_t o;
#pragma unroll
    for (int jj = 0; jj < 8; jj++) o[jj] = t[sj + jj][ri];
    *(short8_t*)(vT + (size_t)(r0 + ri) * SEQ + s0 + sj) = o;
  }
}

// ============================================================================
// GEMM-shaped flash attention. Block = 1 head x 64 queries (4 waves), each
// wave owns 16 query rows end-to-end (in-register online softmax). 64-key
// chunks: K (64x128) and V^T (128x64) staged cooperatively into LDS via
// global_load_lds with XOR col8 swizzle (conflict-free b128 frag reads).
// q/k read from fused qkv buffer (row stride QLD).
// ============================================================================
__global__ __launch_bounds__(256, 3) void attn_kernel(const unsigned short* __restrict__ qb,
                                                      const unsigned short* __restrict__ kb,
                                                      const unsigned short* __restrict__ vT,
                                                      unsigned short* __restrict__ attn_out) {
  const int h = blockIdx.x;
  const int qt = 31 - blockIdx.y;  // heavy qtiles dispatched first
  const int kvh = h >> 2;
  const int q0 = qt * 64;
  const int tid = threadIdx.x;
  const int w = tid >> 6, lane = tid & 63;
  const int quad = lane >> 4, l16 = lane & 15;
  const float SCALE = 0.08838834764831845f;  // 128^-0.5

  __shared__ unsigned short Ks[64 * 128];   // [key][d], XOR col8 swizzled
  __shared__ unsigned short VTs[128 * 64];  // [d][key], XOR col8 swizzled
  __shared__ unsigned short PTs[4 * 64 * 34];  // per-wave [key][q] stride 34

  unsigned short* pt = &PTs[w * 2176];

  // --- staging address precompute (K: 4 issues x 16 rows; VT: 4 x 32 rows) ---
  const int krow = tid >> 4;                       // 0..15
  const int kc16 = tid & 15;
  const int kgcol = (kc16 ^ (krow & 7)) << 3;
  const unsigned short* kgbase = kb + (size_t)krow * QLD + kvh * 128 + kgcol;
  const int vrow = tid >> 3;                       // 0..31
  const int vc8 = tid & 7;
  const int vgcol = (vc8 ^ (vrow & 7)) << 3;
  const unsigned short* vgbase = vT + (size_t)(kvh * 128 + vrow) * 2048 + vgcol;
  unsigned short* ldsK = Ks + w * 512;
  unsigned short* ldsV = VTs + w * 512;

  // --- Q A-frags from global: wave rows q0 + w*16 + l16 ---
  bf16x8_t aq[4];
  {
    const unsigned short* qp = qb + (size_t)(q0 + w * 16 + l16) * QLD + h * 128 + quad * 8;
#pragma unroll
    for (int ks = 0; ks < 4; ks++)
      aq[ks] = __builtin_bit_cast(bf16x8_t, *(const short8_t*)(qp + ks * 32));
  }

  floatx4_t O[8] = {};
  float m_run[4], l_run[4];
#pragma unroll
  for (int r = 0; r < 4; r++) { m_run[r] = -3e38f; l_run[r] = 0.0f; }

  const int qmin = q0 + w * 16, qmax = qmin + 15;
  int kbeg = q0 - (WINDOW - 1); if (kbeg < 0) kbeg = 0;
  const int c0 = kbeg & ~63;
  const int nch = (q0 + 64 - c0) >> 6;
  const int sa = l16 & 7;

  for (int ci = 0; ci < nch; ci++) {
    const int kb0 = c0 + (ci << 6);
    // ---- cooperative staging: K chunk 16KB + VT chunk 16KB ----
#pragma unroll
    for (int i = 0; i < 4; i++)
      load_lds16(kgbase + (size_t)(kb0 + i * 16) * QLD, ldsK + i * 2048);
#pragma unroll
    for (int i = 0; i < 4; i++)
      load_lds16(vgbase + kb0 + (size_t)(i * 32) * 2048, ldsV + i * 2048);
    __syncthreads();
    // ---- QK: 4 key subtiles x 4 ks ----
    floatx4_t S[4];
#pragma unroll
    for (int j = 0; j < 4; j++) {
      floatx4_t acc = {};
      const int keyrow = j * 16 + l16;
#pragma unroll
      for (int ks = 0; ks < 4; ks++) {
        const int c16 = ((ks << 2) | quad) ^ sa;
        bf16x8_t bfk = __builtin_bit_cast(bf16x8_t,
            *(const short8_t*)(&Ks[keyrow * 128 + c16 * 8]));
        acc = __builtin_amdgcn_mfma_f32_16x16x32_bf16(aq[ks], bfk, acc, 0, 0, 0);
      }
      S[j] = acc;
    }
    // ---- mask (wave-uniform branch; only edge chunks) ----
    const bool need_mask = (kb0 + 63 > qmin) || (qmax - kb0 >= WINDOW);
    if (need_mask) {
#pragma unroll
      for (int j = 0; j < 4; j++) {
        const int key = kb0 + j * 16 + l16;
#pragma unroll
        for (int r = 0; r < 4; r++) {
          const int i = qmin + quad * 4 + r;
          const bool ok = (key <= i) && (i - key < WINDOW);
          S[j][r] = ok ? S[j][r] : -3e38f;
        }
      }
    }
    // ---- in-register online softmax (row = quad*4+r; reduce over 16 lanes) ----
    float mx[4], rs[4], alpha[4];
#pragma unroll
    for (int r = 0; r < 4; r++) {
      float m = S[0][r];
#pragma unroll
      for (int j = 1; j < 4; j++) m = fmaxf(m, S[j][r]);
#pragma unroll
      for (int d = 1; d < 16; d <<= 1) m = fmaxf(m, __shfl_xor(m, d, 16));
      mx[r] = fmaxf(m_run[r], m);
      alpha[r] = __expf(SCALE * (m_run[r] - mx[r]));
      m_run[r] = mx[r];
      rs[r] = 0.0f;
    }
#pragma unroll
    for (int j = 0; j < 4; j++) {
      float p[4];
#pragma unroll
      for (int r = 0; r < 4; r++) {
        const float sv = S[j][r];
        float e = __expf(SCALE * (sv - mx[r]));
        if (need_mask) e = (sv < -1e37f) ? 0.0f : e;
        p[r] = e;
        rs[r] += e;
      }
      uint32* dst = (uint32*)(pt + (j * 16 + l16) * 34 + quad * 4);
      dst[0] = f2bf_bits(p[0]) | (f2bf_bits(p[1]) << 16);
      dst[1] = f2bf_bits(p[2]) | (f2bf_bits(p[3]) << 16);
    }
#pragma unroll
    for (int r = 0; r < 4; r++) {
#pragma unroll
      for (int d = 1; d < 16; d <<= 1) rs[r] += __shfl_xor(rs[r], d, 16);
      l_run[r] = l_run[r] * alpha[r] + rs[r];
    }
#pragma unroll
    for (int nt = 0; nt < 8; nt++)
#pragma unroll
      for (int r = 0; r < 4; r++) O[nt][r] *= alpha[r];
    // same-wave LDS write->read (DS ops wave-in-order); block compiler reordering
    asm volatile("" ::: "memory");
    // ---- PV: k = 64 keys (2 ks), 8 output d-tiles ----
#pragma unroll
    for (int ks = 0; ks < 2; ks++) {
      short8_t as;
#pragma unroll
      for (int jj = 0; jj < 8; jj++)
        as[jj] = (short)pt[(ks * 32 + quad * 8 + jj) * 34 + l16];
      bf16x8_t af = __builtin_bit_cast(bf16x8_t, as);
#pragma unroll
      for (int nt = 0; nt < 8; nt++) {
        const int c8 = (((ks << 2) | quad) ^ sa);
        bf16x8_t bfv = __builtin_bit_cast(bf16x8_t,
            *(const short8_t*)(&VTs[(nt * 16 + l16) * 64 + c8 * 8]));
        O[nt] = __builtin_amdgcn_mfma_f32_16x16x32_bf16(af, bfv, O[nt], 0, 0, 0);
      }
    }
    __syncthreads();  // before next chunk overwrites Ks/VTs
  }
  // ---- epilogue ----
  float inv_l[4];
#pragma unroll
  for (int r = 0; r < 4; r++) inv_l[r] = 1.0f / l_run[r];
#pragma unroll
  for (int nt = 0; nt < 8; nt++)
#pragma unroll
    for (int r = 0; r < 4; r++) {
      float v = O[nt][r] * inv_l[r];
      attn_out[(size_t)(qmin + quad * 4 + r) * 4096 + h * 128 + nt * 16 + l16] =
          (unsigned short)f2bf_bits(v);
    }
}

extern "C" void kernel_launch(void* const* d_in, const int* in_sizes, int n_in,
                              void* d_out, int out_size, void* d_ws, size_t ws_size,
                              hipStream_t stream) {
  (void)in_sizes; (void)n_in; (void)out_size; (void)ws_size;
  const float* x    = (const float*)d_in[0];
  const float* wq   = (const float*)d_in[1];
  const float* wk   = (const float*)d_in[2];
  const float* wv   = (const float*)d_in[3];
  const float* wo   = (const float*)d_in[4];
  const float* cosp = (const float*)d_in[5];
  const float* sinp = (const float*)d_in[6];
  float* out = (float*)d_out;
  char* ws = (char*)d_ws;

  // Region map (reuse; 92.3 MB total, same footprint as before):
  //   wqkvb @0        (50.3MB, dead after QKV gemm)
  //       -> wob  @0        (33.6MB)
  //       -> vTb  @33.6MB   (4.2MB)
  //   xb    @50.3MB   (16.8MB, dead after QKV gemm)
  //       -> attnb @50.3MB  (16.8MB)
  //   qkvb  @67.1MB   (25.2MB: [2048][6144] bf16, rope applied in-gemm)
  unsigned short* wqkvb = (unsigned short*)(ws);
  unsigned short* wob   = (unsigned short*)(ws);
  unsigned short* vTb   = (unsigned short*)(ws + 33554432);
  unsigned short* xb    = (unsigned short*)(ws + 50331648);
  unsigned short* attnb = (unsigned short*)(ws + 50331648);
  unsigned short* qkvb  = (unsigned short*)(ws + 67108864);

  // 1: merged cvt of x, wq, wk, wv (wq rows 0-4095, wk 4096-5119, wv 5120-6143)
  cvt4_kernel<<<16384, 256, 0, stream>>>(
      x, wq, wk, wv,
      xb, wqkvb, wqkvb + (size_t)4096 * 4096, wqkvb + (size_t)5120 * 4096);
  // 2: fused QKV projection + RoPE epilogue (q cols 0-4095, k 4096-5119 roped)
  gemm_bf16<unsigned short, true><<<dim3(48, 16), 256, 0, stream>>>(
      xb, wqkvb, qkvb, SEQ, QLD, DIM, cosp, sinp, 5120);
  // 3: wo cvt (after gemm so wob can overlay dead wqkvb)
  cvt_kernel<<<8192, 256, 0, stream>>>(wo, wob, DIM * NH * HD / 8);
  // 4: v transpose (v = qkvb cols 5120.., ld QLD)
  vtrans_kernel<<<dim3(16, 32), 256, 0, stream>>>(qkvb + 5120, vTb);
  // 5: attention (q = qkvb, k = qkvb+4096, both ld QLD)
  attn_kernel<<<dim3(NH, 32), 256, 0, stream>>>(qkvb, qkvb + 4096, vTb, attnb);
  // 6: output projection
  gemm_bf16<float, false><<<dim3(32, 16), 256, 0, stream>>>(
      attnb, wob, out, SEQ, 4096, DIM, nullptr, nullptr, 0);
}

// Round 2
// 467.866 us; speedup vs baseline: 1.1328x; 1.1289x over previous
//
#include <hip/hip_runtime.h>

#define DIM 4096
#define NH 32
#define NKV 8
#define HD 128
#define WINDOW 1024
#define SEQ 2048
#define QLD 6144  // fused QKV row stride (u16 elems)

typedef unsigned int uint32;
typedef __attribute__((ext_vector_type(8))) short short8_t;
typedef __attribute__((ext_vector_type(8))) __bf16 bf16x8_t;
typedef __attribute__((ext_vector_type(4))) float floatx4_t;

__device__ __forceinline__ uint32 f2bf_bits(float f) {
  uint32 u = __builtin_bit_cast(uint32, f);
  return (u + 0x7fffu + ((u >> 16) & 1u)) >> 16;
}
__device__ __forceinline__ float bf2f(unsigned short b) {
  return __builtin_bit_cast(float, ((uint32)b) << 16);
}

template <class X, class Y> struct same_t { static constexpr bool v = false; };
template <class X> struct same_t<X, X> { static constexpr bool v = true; };

__device__ __forceinline__ void load_lds16(const unsigned short* g, unsigned short* l) {
  __builtin_amdgcn_global_load_lds((__attribute__((address_space(1))) void*)g,
                                   (__attribute__((address_space(3))) void*)l, 16, 0, 0);
}

// ============================================================================
// bf16 GEMM (m97-style): C[M,N] = A[M,K]*B[N,K]^T, global_load_lds width-16
// staging, XOR col8 swizzle, 128x(32*JT) tile, BK=64, 4 waves x (4xJT) MFMA.
// JT = j-tiles (16 cols) per wave: JT=4 -> 128-wide tile, JT=6 -> 192-wide.
// Grid must be sized so blocks = 2/CU exactly (512 on MI355X): launch_bounds
// (256,2) pins 2 waves/EU so the register allocator can't drop residency.
// ROPE=true: apply rotary embedding in the epilogue for cols < rope_ncols
// (pair (2d,2d+1) lives in lanes l16^1 -> one shfl_xor; applied to fp32 acc
// before the single bf16 round).
// ============================================================================
template <typename TC, bool ROPE, int JT>
__global__ __launch_bounds__(256, 2) void gemm_bf16(const unsigned short* __restrict__ A,
                                                    const unsigned short* __restrict__ B,
                                                    TC* __restrict__ C,
                                                    int M, int N, int K,
                                                    const float* __restrict__ cosp,
                                                    const float* __restrict__ sinp,
                                                    int rope_ncols) {
  constexpr int BN = 32 * JT;              // block tile width
  constexpr int WN = 16 * JT;              // per-wave tile width
  __shared__ unsigned short As[128 * 64];
  __shared__ unsigned short Bs[BN * 64];
  const int tid = threadIdx.x;
  const int lane = tid & 63, w = tid >> 6;
  const int quad = lane >> 4, l16 = lane & 15;
  const int wm = w >> 1, wn = w & 1;
  const size_t m0 = (size_t)blockIdx.y * 128, n0 = (size_t)blockIdx.x * BN;

  const int srow = tid >> 3;
  const int scol = ((tid & 7) ^ (srow & 7)) << 3;
  const unsigned short* Abase = A + (m0 + srow) * (size_t)K + scol;
  const unsigned short* Bbase = B + (n0 + srow) * (size_t)K + scol;
  unsigned short* ldsA = As + (tid >> 6) * 512;
  unsigned short* ldsB = Bs + (tid >> 6) * 512;

  const int sa = l16 & 7;
  const int raA = wm * 64 + l16;
  const int raB = wn * WN + l16;   // WN multiple of 16 -> (row&7)==(l16&7), swizzle consistent

  floatx4_t acc[4][JT] = {};

  const int nk = K >> 6;
  for (int kt = 0; kt < nk; kt++) {
    const int kbase = kt << 6;
#pragma unroll
    for (int i = 0; i < 4; i++)
      load_lds16(Abase + kbase + (size_t)(i * 32) * K, ldsA + i * 2048);
#pragma unroll
    for (int i = 0; i < JT; i++)
      load_lds16(Bbase + kbase + (size_t)(i * 32) * K, ldsB + i * 2048);
    __syncthreads();
#pragma unroll
    for (int ks = 0; ks < 2; ks++) {
      bf16x8_t af[4], bfg[JT];
#pragma unroll
      for (int i = 0; i < 4; i++) {
        const int colA = (((ks << 2) | quad) ^ sa) << 3;
        af[i] = __builtin_bit_cast(bf16x8_t,
            *(const short8_t*)(&As[(raA + i * 16) * 64 + colA]));
      }
#pragma unroll
      for (int j = 0; j < JT; j++) {
        const int colB = (((ks << 2) | quad) ^ sa) << 3;
        bfg[j] = __builtin_bit_cast(bf16x8_t,
            *(const short8_t*)(&Bs[(raB + j * 16) * 64 + colB]));
      }
#pragma unroll
      for (int i = 0; i < 4; i++)
#pragma unroll
        for (int j = 0; j < JT; j++)
          acc[i][j] = __builtin_amdgcn_mfma_f32_16x16x32_bf16(af[i], bfg[j], acc[i][j], 0, 0, 0);
    }
    __syncthreads();
  }
#pragma unroll
  for (int i = 0; i < 4; i++)
#pragma unroll
    for (int j = 0; j < JT; j++) {
      const int colb = (int)n0 + wn * WN + j * 16;  // wave-uniform
      const bool do_rope = ROPE && (colb < rope_ncols);
#pragma unroll
      for (int r = 0; r < 4; r++) {
        size_t row = m0 + wm * 64 + i * 16 + quad * 4 + r;
        size_t col = n0 + wn * WN + j * 16 + l16;
        float v = acc[i][j][r];
        if constexpr (ROPE) {
          if (do_rope) {  // wave-uniform branch (16-col tile never straddles 5120)
            float pv = __shfl_xor(v, 1);
            const int d = ((int)col & 127) >> 1;
            const float c = cosp[row * 64 + d];
            const float s = sinp[row * 64 + d];
            v = ((int)col & 1) ? (pv * s + v * c) : (v * c - pv * s);
          }
        }
        if constexpr (same_t<TC, float>::v)
          C[row * (size_t)N + col] = v;
        else
          C[row * (size_t)N + col] = (unsigned short)f2bf_bits(v);
      }
    }
}

// fp32 -> bf16 convert, 8 elems/thread
__global__ __launch_bounds__(256) void cvt_kernel(const float* __restrict__ in,
                                                  unsigned short* __restrict__ out, int n8) {
  int idx = blockIdx.x * 256 + threadIdx.x;
  if (idx >= n8) return;
  const float4* p = (const float4*)in + (size_t)idx * 2;
  float4 a = p[0], b = p[1];
  uint32 w0 = f2bf_bits(a.x) | (f2bf_bits(a.y) << 16);
  uint32 w1 = f2bf_bits(a.z) | (f2bf_bits(a.w) << 16);
  uint32 w2 = f2bf_bits(b.x) | (f2bf_bits(b.y) << 16);
  uint32 w3 = f2bf_bits(b.z) | (f2bf_bits(b.w) << 16);
  ((uint4*)out)[idx] = make_uint4(w0, w1, w2, w3);
}

// Merged fp32->bf16 convert for {x, wq, wk, wv}: region-dispatched by block.
// Block counts: x 4096, wq 8192, wk 2048, wv 2048 (all exact multiples).
__global__ __launch_bounds__(256) void cvt4_kernel(const float* __restrict__ s0,
                                                   const float* __restrict__ s1,
                                                   const float* __restrict__ s2,
                                                   const float* __restrict__ s3,
                                                   unsigned short* __restrict__ d0,
                                                   unsigned short* __restrict__ d1,
                                                   unsigned short* __restrict__ d2,
                                                   unsigned short* __restrict__ d3) {
  const int b = blockIdx.x;
  const float* src;
  unsigned short* dst;
  int rb;
  if (b < 4096)        { src = s0; dst = d0; rb = b; }
  else if (b < 12288)  { src = s1; dst = d1; rb = b - 4096; }
  else if (b < 14336)  { src = s2; dst = d2; rb = b - 12288; }
  else                 { src = s3; dst = d3; rb = b - 14336; }
  const int idx = rb * 256 + threadIdx.x;
  const float4* p = (const float4*)src + (size_t)idx * 2;
  float4 a = p[0], bb = p[1];
  uint32 w0 = f2bf_bits(a.x) | (f2bf_bits(a.y) << 16);
  uint32 w1 = f2bf_bits(a.z) | (f2bf_bits(a.w) << 16);
  uint32 w2 = f2bf_bits(bb.x) | (f2bf_bits(bb.y) << 16);
  uint32 w3 = f2bf_bits(bb.z) | (f2bf_bits(bb.w) << 16);
  ((uint4*)dst)[idx] = make_uint4(w0, w1, w2, w3);
}

// v [s][r] (ld QLD, v = qkvb col 5120) -> vT [r][s], 64x64 LDS tiles
__global__ __launch_bounds__(256) void vtrans_kernel(const unsigned short* __restrict__ v,
                                                     unsigned short* __restrict__ vT) {
  __shared__ unsigned short t[64][72];
  const int s0 = blockIdx.y * 64, r0 = blockIdx.x * 64;
  const int tid = threadIdx.x;
#pragma unroll
  for (int it = 0; it < 2; it++) {
    int f = it * 256 + tid;
    int si = f >> 3, cj = (f & 7) << 3;
    *(short8_t*)(&t[si][cj]) = *(const short8_t*)(v + (size_t)(s0 + si) * QLD + r0 + cj);
  }
  __syncthreads();
#pragma unroll
  for (int it = 0; it < 2; it++) {
    int f = it * 256 + tid;
    int ri = f >> 3, sj = (f & 7) << 3;
    short8_t o;
#pragma unroll
    for (int jj = 0; jj < 8; jj++) o[jj] = t[sj + jj][ri];
    *(short8_t*)(vT + (size_t)(r0 + ri) * SEQ + s0 + sj) = o;
  }
}

// ============================================================================
// GEMM-shaped flash attention. Block = 1 head x 64 queries (4 waves), each
// wave owns 16 query rows end-to-end (in-register online softmax). 64-key
// chunks: K (64x128) and V^T (128x64) staged cooperatively into LDS via
// global_load_lds with XOR col8 swizzle (conflict-free b128 frag reads).
// q/k read from fused qkv buffer (row stride QLD).
// ============================================================================
__global__ __launch_bounds__(256, 3) void attn_kernel(const unsigned short* __restrict__ qb,
                                                      const unsigned short* __restrict__ kb,
                                                      const unsigned short* __restrict__ vT,
                                                      unsigned short* __restrict__ attn_out) {
  const int h = blockIdx.x;
  const int qt = 31 - blockIdx.y;  // heavy qtiles dispatched first
  const int kvh = h >> 2;
  const int q0 = qt * 64;
  const int tid = threadIdx.x;
  const int w = tid >> 6, lane = tid & 63;
  const int quad = lane >> 4, l16 = lane & 15;
  const float SCALE = 0.08838834764831845f;  // 128^-0.5

  __shared__ unsigned short Ks[64 * 128];   // [key][d], XOR col8 swizzled
  __shared__ unsigned short VTs[128 * 64];  // [d][key], XOR col8 swizzled
  __shared__ unsigned short PTs[4 * 64 * 34];  // per-wave [key][q] stride 34

  unsigned short* pt = &PTs[w * 2176];

  // --- staging address precompute (K: 4 issues x 16 rows; VT: 4 x 32 rows) ---
  const int krow = tid >> 4;                       // 0..15
  const int kc16 = tid & 15;
  const int kgcol = (kc16 ^ (krow & 7)) << 3;
  const unsigned short* kgbase = kb + (size_t)krow * QLD + kvh * 128 + kgcol;
  const int vrow = tid >> 3;                       // 0..31
  const int vc8 = tid & 7;
  const int vgcol = (vc8 ^ (vrow & 7)) << 3;
  const unsigned short* vgbase = vT + (size_t)(kvh * 128 + vrow) * 2048 + vgcol;
  unsigned short* ldsK = Ks + w * 512;
  unsigned short* ldsV = VTs + w * 512;

  // --- Q A-frags from global: wave rows q0 + w*16 + l16 ---
  bf16x8_t aq[4];
  {
    const unsigned short* qp = qb + (size_t)(q0 + w * 16 + l16) * QLD + h * 128 + quad * 8;
#pragma unroll
    for (int ks = 0; ks < 4; ks++)
      aq[ks] = __builtin_bit_cast(bf16x8_t, *(const short8_t*)(qp + ks * 32));
  }

  floatx4_t O[8] = {};
  float m_run[4], l_run[4];
#pragma unroll
  for (int r = 0; r < 4; r++) { m_run[r] = -3e38f; l_run[r] = 0.0f; }

  const int qmin = q0 + w * 16, qmax = qmin + 15;
  int kbeg = q0 - (WINDOW - 1); if (kbeg < 0) kbeg = 0;
  const int c0 = kbeg & ~63;
  const int nch = (q0 + 64 - c0) >> 6;
  const int sa = l16 & 7;

  for (int ci = 0; ci < nch; ci++) {
    const int kb0 = c0 + (ci << 6);
    // ---- cooperative staging: K chunk 16KB + VT chunk 16KB ----
#pragma unroll
    for (int i = 0; i < 4; i++)
      load_lds16(kgbase + (size_t)(kb0 + i * 16) * QLD, ldsK + i * 2048);
#pragma unroll
    for (int i = 0; i < 4; i++)
      load_lds16(vgbase + kb0 + (size_t)(i * 32) * 2048, ldsV + i * 2048);
    __syncthreads();
    // ---- QK: 4 key subtiles x 4 ks ----
    floatx4_t S[4];
#pragma unroll
    for (int j = 0; j < 4; j++) {
      floatx4_t acc = {};
      const int keyrow = j * 16 + l16;
#pragma unroll
      for (int ks = 0; ks < 4; ks++) {
        const int c16 = ((ks << 2) | quad) ^ sa;
        bf16x8_t bfk = __builtin_bit_cast(bf16x8_t,
            *(const short8_t*)(&Ks[keyrow * 128 + c16 * 8]));
        acc = __builtin_amdgcn_mfma_f32_16x16x32_bf16(aq[ks], bfk, acc, 0, 0, 0);
      }
      S[j] = acc;
    }
    // ---- mask (wave-uniform branch; only edge chunks) ----
    const bool need_mask = (kb0 + 63 > qmin) || (qmax - kb0 >= WINDOW);
    if (need_mask) {
#pragma unroll
      for (int j = 0; j < 4; j++) {
        const int key = kb0 + j * 16 + l16;
#pragma unroll
        for (int r = 0; r < 4; r++) {
          const int i = qmin + quad * 4 + r;
          const bool ok = (key <= i) && (i - key < WINDOW);
          S[j][r] = ok ? S[j][r] : -3e38f;
        }
      }
    }
    // ---- in-register online softmax (row = quad*4+r; reduce over 16 lanes) ----
    float mx[4], rs[4], alpha[4];
#pragma unroll
    for (int r = 0; r < 4; r++) {
      float m = S[0][r];
#pragma unroll
      for (int j = 1; j < 4; j++) m = fmaxf(m, S[j][r]);
#pragma unroll
      for (int d = 1; d < 16; d <<= 1) m = fmaxf(m, __shfl_xor(m, d, 16));
      mx[r] = fmaxf(m_run[r], m);
      alpha[r] = __expf(SCALE * (m_run[r] - mx[r]));
      m_run[r] = mx[r];
      rs[r] = 0.0f;
    }
#pragma unroll
    for (int j = 0; j < 4; j++) {
      float p[4];
#pragma unroll
      for (int r = 0; r < 4; r++) {
        const float sv = S[j][r];
        float e = __expf(SCALE * (sv - mx[r]));
        if (need_mask) e = (sv < -1e37f) ? 0.0f : e;
        p[r] = e;
        rs[r] += e;
      }
      uint32* dst = (uint32*)(pt + (j * 16 + l16) * 34 + quad * 4);
      dst[0] = f2bf_bits(p[0]) | (f2bf_bits(p[1]) << 16);
      dst[1] = f2bf_bits(p[2]) | (f2bf_bits(p[3]) << 16);
    }
#pragma unroll
    for (int r = 0; r < 4; r++) {
#pragma unroll
      for (int d = 1; d < 16; d <<= 1) rs[r] += __shfl_xor(rs[r], d, 16);
      l_run[r] = l_run[r] * alpha[r] + rs[r];
    }
#pragma unroll
    for (int nt = 0; nt < 8; nt++)
#pragma unroll
      for (int r = 0; r < 4; r++) O[nt][r] *= alpha[r];
    // same-wave LDS write->read (DS ops wave-in-order); block compiler reordering
    asm volatile("" ::: "memory");
    // ---- PV: k = 64 keys (2 ks), 8 output d-tiles ----
#pragma unroll
    for (int ks = 0; ks < 2; ks++) {
      short8_t as;
#pragma unroll
      for (int jj = 0; jj < 8; jj++)
        as[jj] = (short)pt[(ks * 32 + quad * 8 + jj) * 34 + l16];
      bf16x8_t af = __builtin_bit_cast(bf16x8_t, as);
#pragma unroll
      for (int nt = 0; nt < 8; nt++) {
        const int c8 = (((ks << 2) | quad) ^ sa);
        bf16x8_t bfv = __builtin_bit_cast(bf16x8_t,
            *(const short8_t*)(&VTs[(nt * 16 + l16) * 64 + c8 * 8]));
        O[nt] = __builtin_amdgcn_mfma_f32_16x16x32_bf16(af, bfv, O[nt], 0, 0, 0);
      }
    }
    __syncthreads();  // before next chunk overwrites Ks/VTs
  }
  // ---- epilogue ----
  float inv_l[4];
#pragma unroll
  for (int r = 0; r < 4; r++) inv_l[r] = 1.0f / l_run[r];
#pragma unroll
  for (int nt = 0; nt < 8; nt++)
#pragma unroll
    for (int r = 0; r < 4; r++) {
      float v = O[nt][r] * inv_l[r];
      attn_out[(size_t)(qmin + quad * 4 + r) * 4096 + h * 128 + nt * 16 + l16] =
          (unsigned short)f2bf_bits(v);
    }
}

extern "C" void kernel_launch(void* const* d_in, const int* in_sizes, int n_in,
                              void* d_out, int out_size, void* d_ws, size_t ws_size,
                              hipStream_t stream) {
  (void)in_sizes; (void)n_in; (void)out_size; (void)ws_size;
  const float* x    = (const float*)d_in[0];
  const float* wq   = (const float*)d_in[1];
  const float* wk   = (const float*)d_in[2];
  const float* wv   = (const float*)d_in[3];
  const float* wo   = (const float*)d_in[4];
  const float* cosp = (const float*)d_in[5];
  const float* sinp = (const float*)d_in[6];
  float* out = (float*)d_out;
  char* ws = (char*)d_ws;

  // Region map (reuse; 92.3 MB total):
  //   wqkvb @0        (50.3MB, dead after QKV gemm)
  //       -> wob  @0        (33.6MB)
  //       -> vTb  @33.6MB   (4.2MB)
  //   xb    @50.3MB   (16.8MB, dead after QKV gemm)
  //       -> attnb @50.3MB  (16.8MB)
  //   qkvb  @67.1MB   (25.2MB: [2048][6144] bf16, rope applied in-gemm)
  unsigned short* wqkvb = (unsigned short*)(ws);
  unsigned short* wob   = (unsigned short*)(ws);
  unsigned short* vTb   = (unsigned short*)(ws + 33554432);
  unsigned short* xb    = (unsigned short*)(ws + 50331648);
  unsigned short* attnb = (unsigned short*)(ws + 50331648);
  unsigned short* qkvb  = (unsigned short*)(ws + 67108864);

  // 1: merged cvt of x, wq, wk, wv (wq rows 0-4095, wk 4096-5119, wv 5120-6143)
  cvt4_kernel<<<16384, 256, 0, stream>>>(
      x, wq, wk, wv,
      xb, wqkvb, wqkvb + (size_t)4096 * 4096, wqkvb + (size_t)5120 * 4096);
  // 2: fused QKV projection + RoPE epilogue, 128x192 tile -> 32x16 = 512
  //    blocks = exactly 2/CU (uniform single round, no residency-quantization
  //    tail like the 768-block 128x128 version)
  gemm_bf16<unsigned short, true, 6><<<dim3(32, 16), 256, 0, stream>>>(
      xb, wqkvb, qkvb, SEQ, QLD, DIM, cosp, sinp, 5120);
  // 3: wo cvt (after gemm so wob can overlay dead wqkvb)
  cvt_kernel<<<8192, 256, 0, stream>>>(wo, wob, DIM * NH * HD / 8);
  // 4: v transpose (v = qkvb cols 5120.., ld QLD)
  vtrans_kernel<<<dim3(16, 32), 256, 0, stream>>>(qkvb + 5120, vTb);
  // 5: attention (q = qkvb, k = qkvb+4096, both ld QLD)
  attn_kernel<<<dim3(NH, 32), 256, 0, stream>>>(qkvb, qkvb + 4096, vTb, attnb);
  // 6: output projection (128x128 tile, 32x16 = 512 blocks, 2/CU)
  gemm_bf16<float, false, 4><<<dim3(32, 16), 256, 0, stream>>>(
      attnb, wob, out, SEQ, 4096, DIM, nullptr, nullptr, 0);
}

// Round 3
// 465.050 us; speedup vs baseline: 1.1396x; 1.0061x over previous
//
#include <hip/hip_runtime.h>

#define DIM 4096
#define NH 32
#define NKV 8
#define HD 128
#define WINDOW 1024
#define SEQ 2048
#define QLD 6144  // fused QKV row stride (u16 elems)

typedef unsigned int uint32;
typedef __attribute__((ext_vector_type(8))) short short8_t;
typedef __attribute__((ext_vector_type(8))) __bf16 bf16x8_t;
typedef __attribute__((ext_vector_type(4))) float floatx4_t;

__device__ __forceinline__ uint32 f2bf_bits(float f) {
  uint32 u = __builtin_bit_cast(uint32, f);
  return (u + 0x7fffu + ((u >> 16) & 1u)) >> 16;
}
__device__ __forceinline__ float bf2f(unsigned short b) {
  return __builtin_bit_cast(float, ((uint32)b) << 16);
}

template <class X, class Y> struct same_t { static constexpr bool v = false; };
template <class X> struct same_t<X, X> { static constexpr bool v = true; };

__device__ __forceinline__ void load_lds16(const unsigned short* g, unsigned short* l) {
  __builtin_amdgcn_global_load_lds((__attribute__((address_space(1))) void*)g,
                                   (__attribute__((address_space(3))) void*)l, 16, 0, 0);
}

// ============================================================================
// bf16 GEMM (m97-style): C[M,N] = A[M,K]*B[N,K]^T, global_load_lds width-16
// staging, XOR col8 swizzle, 128x(32*JT) tile, BK=64, 4 waves x (4xJT) MFMA.
// JT=6 -> 192-wide tile (QKV: 32x16=512 blocks = 2/CU uniform);
// JT=4 -> 128-wide (WO: 32x16=512 blocks).  [874 TF measured = structure
// ceiling; do not perturb]
// ============================================================================
template <typename TC, bool ROPE, int JT>
__global__ __launch_bounds__(256, 2) void gemm_bf16(const unsigned short* __restrict__ A,
                                                    const unsigned short* __restrict__ B,
                                                    TC* __restrict__ C,
                                                    int M, int N, int K,
                                                    const float* __restrict__ cosp,
                                                    const float* __restrict__ sinp,
                                                    int rope_ncols) {
  constexpr int BN = 32 * JT;              // block tile width
  constexpr int WN = 16 * JT;              // per-wave tile width
  __shared__ unsigned short As[128 * 64];
  __shared__ unsigned short Bs[BN * 64];
  const int tid = threadIdx.x;
  const int lane = tid & 63, w = tid >> 6;
  const int quad = lane >> 4, l16 = lane & 15;
  const int wm = w >> 1, wn = w & 1;
  const size_t m0 = (size_t)blockIdx.y * 128, n0 = (size_t)blockIdx.x * BN;

  const int srow = tid >> 3;
  const int scol = ((tid & 7) ^ (srow & 7)) << 3;
  const unsigned short* Abase = A + (m0 + srow) * (size_t)K + scol;
  const unsigned short* Bbase = B + (n0 + srow) * (size_t)K + scol;
  unsigned short* ldsA = As + (tid >> 6) * 512;
  unsigned short* ldsB = Bs + (tid >> 6) * 512;

  const int sa = l16 & 7;
  const int raA = wm * 64 + l16;
  const int raB = wn * WN + l16;   // WN multiple of 16 -> swizzle consistent

  floatx4_t acc[4][JT] = {};

  const int nk = K >> 6;
  for (int kt = 0; kt < nk; kt++) {
    const int kbase = kt << 6;
#pragma unroll
    for (int i = 0; i < 4; i++)
      load_lds16(Abase + kbase + (size_t)(i * 32) * K, ldsA + i * 2048);
#pragma unroll
    for (int i = 0; i < JT; i++)
      load_lds16(Bbase + kbase + (size_t)(i * 32) * K, ldsB + i * 2048);
    __syncthreads();
#pragma unroll
    for (int ks = 0; ks < 2; ks++) {
      bf16x8_t af[4], bfg[JT];
#pragma unroll
      for (int i = 0; i < 4; i++) {
        const int colA = (((ks << 2) | quad) ^ sa) << 3;
        af[i] = __builtin_bit_cast(bf16x8_t,
            *(const short8_t*)(&As[(raA + i * 16) * 64 + colA]));
      }
#pragma unroll
      for (int j = 0; j < JT; j++) {
        const int colB = (((ks << 2) | quad) ^ sa) << 3;
        bfg[j] = __builtin_bit_cast(bf16x8_t,
            *(const short8_t*)(&Bs[(raB + j * 16) * 64 + colB]));
      }
#pragma unroll
      for (int i = 0; i < 4; i++)
#pragma unroll
        for (int j = 0; j < JT; j++)
          acc[i][j] = __builtin_amdgcn_mfma_f32_16x16x32_bf16(af[i], bfg[j], acc[i][j], 0, 0, 0);
    }
    __syncthreads();
  }
#pragma unroll
  for (int i = 0; i < 4; i++)
#pragma unroll
    for (int j = 0; j < JT; j++) {
      const int colb = (int)n0 + wn * WN + j * 16;  // wave-uniform
      const bool do_rope = ROPE && (colb < rope_ncols);
#pragma unroll
      for (int r = 0; r < 4; r++) {
        size_t row = m0 + wm * 64 + i * 16 + quad * 4 + r;
        size_t col = n0 + wn * WN + j * 16 + l16;
        float v = acc[i][j][r];
        if constexpr (ROPE) {
          if (do_rope) {  // wave-uniform branch (16-col tile never straddles 5120)
            float pv = __shfl_xor(v, 1);
            const int d = ((int)col & 127) >> 1;
            const float c = cosp[row * 64 + d];
            const float s = sinp[row * 64 + d];
            v = ((int)col & 1) ? (pv * s + v * c) : (v * c - pv * s);
          }
        }
        if constexpr (same_t<TC, float>::v)
          C[row * (size_t)N + col] = v;
        else
          C[row * (size_t)N + col] = (unsigned short)f2bf_bits(v);
      }
    }
}

// Merged fp32->bf16 convert for {x, wq, wk, wv}: region-dispatched by block.
// Block counts: x 4096, wq 8192, wk 2048, wv 2048 (all exact multiples).
__global__ __launch_bounds__(256) void cvt4_kernel(const float* __restrict__ s0,
                                                   const float* __restrict__ s1,
                                                   const float* __restrict__ s2,
                                                   const float* __restrict__ s3,
                                                   unsigned short* __restrict__ d0,
                                                   unsigned short* __restrict__ d1,
                                                   unsigned short* __restrict__ d2,
                                                   unsigned short* __restrict__ d3) {
  const int b = blockIdx.x;
  const float* src;
  unsigned short* dst;
  int rb;
  if (b < 4096)        { src = s0; dst = d0; rb = b; }
  else if (b < 12288)  { src = s1; dst = d1; rb = b - 4096; }
  else if (b < 14336)  { src = s2; dst = d2; rb = b - 12288; }
  else                 { src = s3; dst = d3; rb = b - 14336; }
  const int idx = rb * 256 + threadIdx.x;
  const float4* p = (const float4*)src + (size_t)idx * 2;
  float4 a = p[0], bb = p[1];
  uint32 w0 = f2bf_bits(a.x) | (f2bf_bits(a.y) << 16);
  uint32 w1 = f2bf_bits(a.z) | (f2bf_bits(a.w) << 16);
  uint32 w2 = f2bf_bits(bb.x) | (f2bf_bits(bb.y) << 16);
  uint32 w3 = f2bf_bits(bb.z) | (f2bf_bits(bb.w) << 16);
  ((uint4*)dst)[idx] = make_uint4(w0, w1, w2, w3);
}

// ============================================================================
// Merged post-QKV-GEMM launch: blocks [0,8192) convert wo fp32->bf16 into wob
// (overlaying dead wqkvb); blocks [8192,8704) transpose v (qkvb col 5120,
// ld QLD) into vT[r][s]. Both depend only on the QKV GEMM; saves one launch.
// ============================================================================
__global__ __launch_bounds__(256) void epi_kernel(const float* __restrict__ wo,
                                                  unsigned short* __restrict__ wob,
                                                  const unsigned short* __restrict__ v,
                                                  unsigned short* __restrict__ vT) {
  __shared__ unsigned short t[64][72];
  const int b = blockIdx.x;
  const int tid = threadIdx.x;
  if (b < 8192) {
    const int idx = b * 256 + tid;
    const float4* p = (const float4*)wo + (size_t)idx * 2;
    float4 a = p[0], bb = p[1];
    uint32 w0 = f2bf_bits(a.x) | (f2bf_bits(a.y) << 16);
    uint32 w1 = f2bf_bits(a.z) | (f2bf_bits(a.w) << 16);
    uint32 w2 = f2bf_bits(bb.x) | (f2bf_bits(bb.y) << 16);
    uint32 w3 = f2bf_bits(bb.z) | (f2bf_bits(bb.w) << 16);
    ((uint4*)wob)[idx] = make_uint4(w0, w1, w2, w3);
    return;
  }
  const int bx = b - 8192;
  const int r0 = (bx & 15) * 64, s0 = (bx >> 4) * 64;
#pragma unroll
  for (int it = 0; it < 2; it++) {
    int f = it * 256 + tid;
    int si = f >> 3, cj = (f & 7) << 3;
    *(short8_t*)(&t[si][cj]) = *(const short8_t*)(v + (size_t)(s0 + si) * QLD + r0 + cj);
  }
  __syncthreads();
#pragma unroll
  for (int it = 0; it < 2; it++) {
    int f = it * 256 + tid;
    int ri = f >> 3, sj = (f & 7) << 3;
    short8_t o;
#pragma unroll
    for (int jj = 0; jj < 8; jj++) o[jj] = t[sj + jj][ri];
    *(short8_t*)(vT + (size_t)(r0 + ri) * SEQ + s0 + sj) = o;
  }
}

// ============================================================================
// GEMM-shaped flash attention, QBLK=128: block = 1 head x 128 queries
// (8 waves, 512 threads), each wave owns 16 query rows end-to-end
// (in-register online softmax). 64-key chunks staged once per 128 queries
// (2x the compute per staging vs QBLK=64). Per-wave P bridge in LDS with
// [q][key] layout (stride 72 u16 = 144B): 16 scalar b16 writes, then the PV
// A-fragments are 2 contiguous ds_read_b128 (16B-aligned, ~2-way banks).
// Wave-uniform dead-chunk skip for window edges; setprio(1) around MFMA.
// ============================================================================
__global__ __launch_bounds__(512, 4) void attn_kernel(const unsigned short* __restrict__ qb,
                                                      const unsigned short* __restrict__ kb,
                                                      const unsigned short* __restrict__ vT,
                                                      unsigned short* __restrict__ attn_out) {
  const int h = blockIdx.x;
  const int qt = 15 - blockIdx.y;  // heavy qtiles dispatched first
  const int kvh = h >> 2;
  const int q0 = qt * 128;
  const int tid = threadIdx.x;
  const int w = tid >> 6, lane = tid & 63;
  const int quad = lane >> 4, l16 = lane & 15;
  const float SCALE = 0.08838834764831845f;  // 128^-0.5

  __shared__ unsigned short Ks[64 * 128];     // [key][d], XOR col8 swizzled
  __shared__ unsigned short VTs[128 * 64];    // [d][key], XOR col8 swizzled
  __shared__ unsigned short PTs[8 * 16 * 72]; // per-wave [q][key] stride 72

  unsigned short* pt = &PTs[w * 1152];

  // --- staging address precompute (512 threads: K 2 issues x 32 rows;
  //     VT 2 issues x 64 rows; each issue = 8KB) ---
  const int krow = tid >> 4;                       // 0..31
  const int kc16 = tid & 15;
  const int kgcol = (kc16 ^ (krow & 7)) << 3;
  const unsigned short* kgbase = kb + (size_t)krow * QLD + kvh * 128 + kgcol;
  const int vrow = tid >> 3;                       // 0..63
  const int vc8 = tid & 7;
  const int vgcol = (vc8 ^ (vrow & 7)) << 3;
  const unsigned short* vgbase = vT + (size_t)(kvh * 128 + vrow) * 2048 + vgcol;
  unsigned short* ldsK = Ks + w * 512;
  unsigned short* ldsV = VTs + w * 512;

  // --- Q A-frags from global: wave rows q0 + w*16 + l16 ---
  bf16x8_t aq[4];
  {
    const unsigned short* qp = qb + (size_t)(q0 + w * 16 + l16) * QLD + h * 128 + quad * 8;
#pragma unroll
    for (int ks = 0; ks < 4; ks++)
      aq[ks] = __builtin_bit_cast(bf16x8_t, *(const short8_t*)(qp + ks * 32));
  }

  floatx4_t O[8] = {};
  float m_run[4], l_run[4];
#pragma unroll
  for (int r = 0; r < 4; r++) { m_run[r] = -3e38f; l_run[r] = 0.0f; }

  const int qmin = q0 + w * 16, qmax = qmin + 15;
  int kbeg = q0 - (WINDOW - 1); if (kbeg < 0) kbeg = 0;
  const int c0 = kbeg & ~63;
  const int nch = (q0 + 128 - c0) >> 6;
  const int sa = l16 & 7;

  for (int ci = 0; ci < nch; ci++) {
    const int kb0 = c0 + (ci << 6);
    // ---- cooperative staging: K chunk 16KB + VT chunk 16KB ----
#pragma unroll
    for (int i = 0; i < 2; i++)
      load_lds16(kgbase + (size_t)(kb0 + i * 32) * QLD, ldsK + i * 4096);
#pragma unroll
    for (int i = 0; i < 2; i++)
      load_lds16(vgbase + kb0 + (size_t)(i * 64) * 2048, ldsV + i * 4096);
    __syncthreads();
    // ---- wave-uniform dead-chunk skip (window edges) ----
    const bool alive = (kb0 <= qmax) && (kb0 + 63 >= qmin - (WINDOW - 1));
    if (alive) {
      // ---- QK: 4 key subtiles x 4 ks ----
      floatx4_t S[4];
      __builtin_amdgcn_s_setprio(1);
#pragma unroll
      for (int j = 0; j < 4; j++) {
        floatx4_t acc = {};
        const int keyrow = j * 16 + l16;
#pragma unroll
        for (int ks = 0; ks < 4; ks++) {
          const int c16 = ((ks << 2) | quad) ^ sa;
          bf16x8_t bfk = __builtin_bit_cast(bf16x8_t,
              *(const short8_t*)(&Ks[keyrow * 128 + c16 * 8]));
          acc = __builtin_amdgcn_mfma_f32_16x16x32_bf16(aq[ks], bfk, acc, 0, 0, 0);
        }
        S[j] = acc;
      }
      __builtin_amdgcn_s_setprio(0);
      // ---- mask (wave-uniform branch; only edge chunks) ----
      const bool need_mask = (kb0 + 63 > qmin) || (qmax - kb0 >= WINDOW);
      if (need_mask) {
#pragma unroll
        for (int j = 0; j < 4; j++) {
          const int key = kb0 + j * 16 + l16;
#pragma unroll
          for (int r = 0; r < 4; r++) {
            const int i = qmin + quad * 4 + r;
            const bool ok = (key <= i) && (i - key < WINDOW);
            S[j][r] = ok ? S[j][r] : -3e38f;
          }
        }
      }
      // ---- in-register online softmax (row = quad*4+r; reduce over 16 lanes) ----
      float mx[4], rs[4], alpha[4];
#pragma unroll
      for (int r = 0; r < 4; r++) {
        float m = S[0][r];
#pragma unroll
        for (int j = 1; j < 4; j++) m = fmaxf(m, S[j][r]);
#pragma unroll
        for (int d = 1; d < 16; d <<= 1) m = fmaxf(m, __shfl_xor(m, d, 16));
        mx[r] = fmaxf(m_run[r], m);
        alpha[r] = __expf(SCALE * (m_run[r] - mx[r]));
        m_run[r] = mx[r];
        rs[r] = 0.0f;
      }
#pragma unroll
      for (int j = 0; j < 4; j++) {
        float p[4];
#pragma unroll
        for (int r = 0; r < 4; r++) {
          const float sv = S[j][r];
          float e = __expf(SCALE * (sv - mx[r]));
          if (need_mask) e = (sv < -1e37f) ? 0.0f : e;
          p[r] = e;
          rs[r] += e;
        }
        // P[q][key] scalar writes: q = quad*4+r, key = j*16+l16 (~2-way banks)
#pragma unroll
        for (int r = 0; r < 4; r++)
          pt[(quad * 4 + r) * 72 + j * 16 + l16] = (unsigned short)f2bf_bits(p[r]);
      }
#pragma unroll
      for (int r = 0; r < 4; r++) {
#pragma unroll
        for (int d = 1; d < 16; d <<= 1) rs[r] += __shfl_xor(rs[r], d, 16);
        l_run[r] = l_run[r] * alpha[r] + rs[r];
      }
#pragma unroll
      for (int nt = 0; nt < 8; nt++)
#pragma unroll
        for (int r = 0; r < 4; r++) O[nt][r] *= alpha[r];
      // same-wave LDS write->read (DS ops wave-in-order); block compiler reordering
      asm volatile("" ::: "memory");
      // ---- PV: A-frags = 2 x ds_read_b128 from P[q][key]; 8 output d-tiles ----
      __builtin_amdgcn_s_setprio(1);
#pragma unroll
      for (int ks = 0; ks < 2; ks++) {
        bf16x8_t af = __builtin_bit_cast(bf16x8_t,
            *(const short8_t*)(&pt[l16 * 72 + ks * 32 + quad * 8]));
#pragma unroll
        for (int nt = 0; nt < 8; nt++) {
          const int c8 = (((ks << 2) | quad) ^ sa);
          bf16x8_t bfv = __builtin_bit_cast(bf16x8_t,
              *(const short8_t*)(&VTs[(nt * 16 + l16) * 64 + c8 * 8]));
          O[nt] = __builtin_amdgcn_mfma_f32_16x16x32_bf16(af, bfv, O[nt], 0, 0, 0);
        }
      }
      __builtin_amdgcn_s_setprio(0);
    }
    __syncthreads();  // before next chunk overwrites Ks/VTs
  }
  // ---- epilogue ----
  float inv_l[4];
#pragma unroll
  for (int r = 0; r < 4; r++) inv_l[r] = 1.0f / l_run[r];
#pragma unroll
  for (int nt = 0; nt < 8; nt++)
#pragma unroll
    for (int r = 0; r < 4; r++) {
      float v = O[nt][r] * inv_l[r];
      attn_out[(size_t)(qmin + quad * 4 + r) * 4096 + h * 128 + nt * 16 + l16] =
          (unsigned short)f2bf_bits(v);
    }
}

extern "C" void kernel_launch(void* const* d_in, const int* in_sizes, int n_in,
                              void* d_out, int out_size, void* d_ws, size_t ws_size,
                              hipStream_t stream) {
  (void)in_sizes; (void)n_in; (void)out_size; (void)ws_size;
  const float* x    = (const float*)d_in[0];
  const float* wq   = (const float*)d_in[1];
  const float* wk   = (const float*)d_in[2];
  const float* wv   = (const float*)d_in[3];
  const float* wo   = (const float*)d_in[4];
  const float* cosp = (const float*)d_in[5];
  const float* sinp = (const float*)d_in[6];
  float* out = (float*)d_out;
  char* ws = (char*)d_ws;

  // Region map (reuse; 92.3 MB total):
  //   wqkvb @0        (50.3MB, dead after QKV gemm)
  //       -> wob  @0        (33.6MB)
  //       -> vTb  @33.6MB   (4.2MB)
  //   xb    @50.3MB   (16.8MB, dead after QKV gemm)
  //       -> attnb @50.3MB  (16.8MB)
  //   qkvb  @67.1MB   (25.2MB: [2048][6144] bf16, rope applied in-gemm)
  unsigned short* wqkvb = (unsigned short*)(ws);
  unsigned short* wob   = (unsigned short*)(ws);
  unsigned short* vTb   = (unsigned short*)(ws + 33554432);
  unsigned short* xb    = (unsigned short*)(ws + 50331648);
  unsigned short* attnb = (unsigned short*)(ws + 50331648);
  unsigned short* qkvb  = (unsigned short*)(ws + 67108864);

  // 1: merged cvt of x, wq, wk, wv (wq rows 0-4095, wk 4096-5119, wv 5120-6143)
  cvt4_kernel<<<16384, 256, 0, stream>>>(
      x, wq, wk, wv,
      xb, wqkvb, wqkvb + (size_t)4096 * 4096, wqkvb + (size_t)5120 * 4096);
  // 2: fused QKV projection + RoPE epilogue, 128x192 tile -> 512 blocks (2/CU)
  gemm_bf16<unsigned short, true, 6><<<dim3(32, 16), 256, 0, stream>>>(
      xb, wqkvb, qkvb, SEQ, QLD, DIM, cosp, sinp, 5120);
  // 3: merged wo cvt (blocks 0-8191, wob overlays dead wqkvb) + v transpose
  epi_kernel<<<8704, 256, 0, stream>>>(wo, wob, qkvb + 5120, vTb);
  // 4: attention, QBLK=128 (q = qkvb, k = qkvb+4096, both ld QLD)
  attn_kernel<<<dim3(NH, 16), 512, 0, stream>>>(qkvb, qkvb + 4096, vTb, attnb);
  // 5: output projection (128x128 tile, 512 blocks, 2/CU)
  gemm_bf16<float, false, 4><<<dim3(32, 16), 256, 0, stream>>>(
      attnb, wob, out, SEQ, 4096, DIM, nullptr, nullptr, 0);
}